// Round 22
// baseline (178.247 us; speedup 1.0000x reference)
//
#include <hip/hip_runtime.h>
#include <hip/hip_bf16.h>
#include <math.h>

// Shapes: grd (N=64,C=64,24,24), sat (M=64,C=64,64,64); crop sat[:,:,12:52,12:52] (40x40)
// corr (64,64,17,17); out: [0,4096) similarity f32, [4096,40960) sat_f (64,24,24) f32.
//
// Round-22: UNFUSE exact63 from corr_mfma (r20/r21 post-mortem: per-kernel register
// allocation gives exact63 blocks corr's full 212-reg footprint, and their 64MB fp32
// sat stream evicts gth from L2, slowing corr's latency-critical B-loads; fused cost
// +28us vs +12 serial). exact63 now rides in prep (low-reg, same memory stream,
// no MFMA waves to starve). corr_mfma = pure r17 kernel, grid 512 (107us, 3x repro).
// Single bf16-product corr (near-tie flips only; sim err <2e-4); (63,63) exact.

typedef float f32x16 __attribute__((ext_vector_type(16)));
typedef short short8 __attribute__((ext_vector_type(8)));

// ws layout (float words)
#define SATT_H 0u          // bf16 [m][4 cc][1600 pix][16 c] = 3,276,800 f
#define GRDT_H 3276800u    // bf16 [cc=4][ij=576][n=64][16 c] = 1,179,648 f
#define CORR_O 4456448u    // f32 [m][304][64] = 1,245,184 f
#define WING_O 5701632u    // f32 [289] (m=63 win2 row) -> pad 384
#define GN2_O  5702016u    // f32 [2][64] = 128
#define CEX_O  5702144u    // f32 [289] -> pad 384
#define S2G_O  5702528u    // f32 [m][1600] = 102,400 f

// ---------- P0: fused prep. grid 2977 = 2560 satT + 128 grdT + 289 exact63 ----------
// satT blocks (bid<2560): bf16-ize one sat row-slice -> [m][cc][pix][16c], emit S2
// row partials, zero a disjoint float4 slice of corr+winG.
// grdT blocks (2560..2687): bf16-ize grd -> [cc][ij][n][16c], write gn2p[ch][n].
// exact63 blocks (2688..2976): exact fp32 corr for (m,n)=(63,63) at position p —
// low-register memory-bound path sharing prep's sat stream (L2-friendly).
__global__ __launch_bounds__(256) void prep(const float* __restrict__ sat,
                                            const float* __restrict__ grd,
                                            __hip_bfloat16* __restrict__ sth,
                                            __hip_bfloat16* __restrict__ gth,
                                            float* __restrict__ S2g,
                                            float* __restrict__ gn2p,
                                            float* __restrict__ corrz,
                                            float* __restrict__ correx) {
    __shared__ __hip_bfloat16 shb[32 * 577];      // grdT needs 36,928 B; others use prefix
    int bid = blockIdx.x;
    int tid = threadIdx.x;

    if (bid < 2560) {
        // ---- satT path ----
        {
            int f4 = bid * 122 + tid;
            if (tid < 122 && f4 < 311392)
                ((float4*)corrz)[f4] = make_float4(0.f, 0.f, 0.f, 0.f);
        }
        int m = bid / 40, r = bid % 40;
        const float* base = sat + (size_t)m * 262144 + (12 + r) * 64 + 12;
        for (int k = 0; k < 10; k++) {
            int idx = tid + 256 * k;          // 2560 = 64c * 40w
            int c = idx / 40, w2 = idx % 40;
            shb[w2 * 66 + c] = __float2bfloat16(base[c * 4096 + w2]);
        }
        __syncthreads();
        __hip_bfloat16* dh = sth + (size_t)m * 102400 + r * 640;
        for (int k = 0; k < 10; k++) {
            int idx = tid + 256 * k;          // idx = cc*640 + w2*16 + cl
            int cc = idx / 640, rem = idx - cc * 640;
            int w2 = rem >> 4, cl = rem & 15;
            dh[cc * 25600 + w2 * 16 + cl] = shb[w2 * 66 + cc * 16 + cl];
        }
        if (tid < 40) {
            float s = 0.0f;
            for (int c = 0; c < 64; c++) {
                float v = __bfloat162float(shb[tid * 66 + c]);
                s += v * v;
            }
            S2g[m * 1600 + r * 40 + tid] = s;
        }
    } else if (bid < 2688) {
        // ---- grdT path ----
        __shared__ float red[4];
        int x = bid - 2560;
        int n = x >> 1, ch = x & 1;
        const float* src = grd + (size_t)n * 36864 + ch * 32 * 576;
        float s = 0.0f;
        for (int k = 0; k < 72; k++) {
            int idx = tid + 256 * k;          // idx = cl*576 + ij
            int cl = idx / 576, ij = idx % 576;
            float v = src[idx];
            s += v * v;
            shb[cl * 577 + ij] = __float2bfloat16(v);
        }
        for (int off = 32; off; off >>= 1) s += __shfl_down(s, off);
        if ((tid & 63) == 0) red[tid >> 6] = s;
        __syncthreads();
        if (tid == 0) gn2p[ch * 64 + n] = red[0] + red[1] + red[2] + red[3];
        for (int k = 0; k < 72; k++) {
            int idx = tid + 256 * k;          // idx = ij*32 + cl
            int ij = idx >> 5, cl = idx & 31;
            int c = ch * 32 + cl;
            gth[((size_t)((c >> 4) * 576 + ij)) * 1024 + n * 16 + (c & 15)] = shb[cl * 577 + ij];
        }
    } else {
        // ---- exact63 path ----
        int p = bid - 2688;                   // 0..288
        int hy = p / 17, wx = p % 17;
        const float* satm = sat + (size_t)63 * 262144;
        const float* grdn = grd + (size_t)63 * 36864;
        float dot = 0.0f;
        for (int e = tid; e < 36864; e += 256) {
            int c = e / 576, rem = e - c * 576;
            int i = rem / 24, j = rem - i * 24;
            dot += satm[c * 4096 + (12 + hy + i) * 64 + 12 + wx + j] * grdn[e];
        }
        for (int off = 32; off; off >>= 1) dot += __shfl_down(dot, off);
        float* red4 = (float*)shb;
        if ((tid & 63) == 0) red4[tid >> 6] = dot;
        __syncthreads();
        if (tid == 0) correx[p] = red4[0] + red4[1] + red4[2] + red4[3];
    }
}

// ---------- K1: MFMA corr (r17 core verbatim). grid 512; block 256 ----------
// satW = 19 rows x 40 cols x 16c = 24,320 B linear (only LDS). Waves 0-1: p-tiles
// {w,w+4,w+8}; waves 2-3: {w,w+4} (10 real tiles; tail clamps, stores guarded).
// Both n-tiles per wave (acc 3x2 f32x16 = 96 AGPR). B: per-wave contiguous 1KB
// global loads from gth planes (L2-resident), 3-deep rotating register prefetch.
__global__ __launch_bounds__(256, 2) void corr_mfma(const __hip_bfloat16* __restrict__ sth,
                                                    const __hip_bfloat16* __restrict__ gth,
                                                    float* __restrict__ corr) {
    __shared__ __align__(16) __hip_bfloat16 satW[760 * 16];     // 24,320 B

    int bid = blockIdx.x;
    int xcd = bid & 7, slot = bid >> 3;             // XCD-aware: 8 m per XCD
    int m = xcd * 8 + (slot >> 3), iq = slot & 7;   // 8 i-slices of 3 rows per m
    int tid = threadIdx.x;
    int w = tid >> 6, l = tid & 63;
    int ln31 = l & 31, h = l >> 5;

    int rowbase[3];
#pragma unroll
    for (int t = 0; t < 3; t++) {
        int p = (w + 4 * t) * 32 + ln31;
        if (p > 288) p = 288;                       // tail rows clamp to a valid pixel
        rowbase[t] = (p / 17) * 40 + (p % 17);
    }
    f32x16 acc[3][2];
#pragma unroll
    for (int t = 0; t < 3; t++) {
        acc[t][0] = (f32x16)0.0f;
        acc[t][1] = (f32x16)0.0f;
    }

    // B per-lane address: plane (cc*576 + iq*72 + ijl) of 1024 elems;
    // lane frag = [n = nt*32 + ln31][c = h*8..h*8+7].
    const __hip_bfloat16* gbase = gth + (size_t)(iq * 72) * 1024 + ln31 * 16 + h * 8;

#define BLOADR(B0, B1, CC, IJL) {                                               \
        const __hip_bfloat16* p_ = gbase + ((size_t)(CC) * 576 + (IJL)) * 1024; \
        B0 = *(const short8*)p_;                                                \
        B1 = *(const short8*)(p_ + 512);                                        \
    }
#define COMPUTE(IJL, B0, B1) {                                                  \
        int il_ = (IJL) / 24;                                                   \
        int pixoff_ = il_ * 40 + ((IJL) - il_ * 24);                            \
        if (w < 2) {                                                            \
            _Pragma("unroll")                                                   \
            for (int t = 0; t < 3; t++) {                                       \
                int ao = (rowbase[t] + pixoff_) * 32 + h * 16;                  \
                short8 af = *(const short8*)((const char*)satW + ao);           \
                acc[t][0] = __builtin_amdgcn_mfma_f32_32x32x16_bf16(af, B0, acc[t][0], 0, 0, 0); \
                acc[t][1] = __builtin_amdgcn_mfma_f32_32x32x16_bf16(af, B1, acc[t][1], 0, 0, 0); \
            }                                                                   \
        } else {                                                                \
            _Pragma("unroll")                                                   \
            for (int t = 0; t < 2; t++) {                                       \
                int ao = (rowbase[t] + pixoff_) * 32 + h * 16;                  \
                short8 af = *(const short8*)((const char*)satW + ao);           \
                acc[t][0] = __builtin_amdgcn_mfma_f32_32x32x16_bf16(af, B0, acc[t][0], 0, 0, 0); \
                acc[t][1] = __builtin_amdgcn_mfma_f32_32x32x16_bf16(af, B1, acc[t][1], 0, 0, 0); \
            }                                                                   \
        }                                                                       \
    }

#pragma unroll
    for (int cc = 0; cc < 4; cc++) {
        __syncthreads();                            // prior cc's satW reads done
        // stage satW: 1520 linear 16-B slots from relaid satT
        const __hip_bfloat16* satb = sth + (size_t)m * 102400 + cc * 25600 + iq * 1920;
#pragma unroll
        for (int k2 = 0; k2 < 6; k2++) {
            int s = tid + 256 * k2;
            if (s < 1520) {
                float4 v = *(const float4*)(satb + s * 8);
                *(float4*)((char*)satW + s * 16) = v;
            }
        }
        short8 x0, x1, y0, y1, z0, z1;
        BLOADR(x0, x1, cc, 0);
        BLOADR(y0, y1, cc, 1);
        BLOADR(z0, z1, cc, 2);
        __syncthreads();                            // publish satW

        for (int ijg = 0; ijg < 24; ijg++) {
            int base = ijg * 3;
            COMPUTE(base + 0, x0, x1);
            if (base + 3 < 72) BLOADR(x0, x1, cc, base + 3);
            COMPUTE(base + 1, y0, y1);
            if (base + 4 < 72) BLOADR(y0, y1, cc, base + 4);
            COMPUTE(base + 2, z0, z1);
            if (base + 5 < 72) BLOADR(z0, z1, cc, base + 5);
        }
    }

    int T = (w < 2) ? 3 : 2;
#pragma unroll
    for (int t = 0; t < 3; t++) {
        if (t >= T) break;
        int tile = w + 4 * t;
#pragma unroll
        for (int nt = 0; nt < 2; nt++)
#pragma unroll
            for (int q = 0; q < 16; q++) {
                int prow = tile * 32 + (q & 3) + 8 * (q >> 2) + 4 * h;
                if (prow < 289)
                    atomicAdd(&corr[((size_t)m * 304 + prow) * 64 + nt * 32 + ln31],
                              acc[t][nt][q]);
            }
    }
#undef BLOADR
#undef COMPUTE
}

// ---------- K2: fused win2 + argmax + similarity. grid 64 (m); block 256 ----------
__global__ __launch_bounds__(256) void argsim(const float* __restrict__ corr,
                                              const float* __restrict__ S2g,
                                              const float* __restrict__ gn2p,
                                              float* __restrict__ winG,
                                              float* __restrict__ out) {
    __shared__ float S2[40][41];
    __shared__ float RS[40][18];
    __shared__ float w2[304];
    __shared__ float gn[64];
    __shared__ float fbv[4][64];
    __shared__ int   fbi[4][64];
    int m = blockIdx.x, tid = threadIdx.x;
    for (int k = 0; k < 7; k++) {
        int idx = tid + 256 * k;
        if (idx < 1600) S2[idx / 40][idx % 40] = S2g[m * 1600 + idx];
    }
    if (tid < 64) gn[tid] = gn2p[tid] + gn2p[64 + tid];
    __syncthreads();
    for (int k = 0; k < 3; k++) {
        int idx = tid + 256 * k;
        if (idx < 680) {
            int r = idx / 17, x = idx % 17;
            float s = 0.0f;
            for (int j = 0; j < 24; j++) s += S2[r][x + j];
            RS[r][x] = s;
        }
    }
    __syncthreads();
    for (int k = 0; k < 2; k++) {
        int idx = tid + 256 * k;
        if (idx < 289) {
            int y = idx / 17, x = idx % 17;
            float s = 0.0f;
            for (int i2 = 0; i2 < 24; i2++) s += RS[y + i2][x];
            w2[idx] = s;
            if (m == 63) winG[idx] = s;
        }
    }
    __syncthreads();
    int n = tid & 63, pg = tid >> 6;
    float bv = -3.0e38f;
    int bi = 1 << 30;
    for (int p = pg; p < 289; p += 4) {
        float v = corr[((size_t)m * 304 + p) * 64 + n];
        if (v > bv) { bv = v; bi = p; }   // ascending p within group: first occurrence
    }
    fbv[pg][n] = bv;
    fbi[pg][n] = bi;
    __syncthreads();
    if (pg == 0) {
        for (int q = 1; q < 4; q++) {
            float ov = fbv[q][n];
            int oi = fbi[q][n];
            if (ov > bv || (ov == bv && oi < bi)) { bv = ov; bi = oi; }
        }
        out[m * 64 + n] = bv / (fmaxf(sqrtf(w2[bi]), 1e-12f) * fmaxf(sqrtf(gn[n]), 1e-12f));
    }
}

// ---------- K3: (63,63) exact argmax + sim fix + patch copy. grid 144 ----------
__global__ __launch_bounds__(256) void copy_patch(const float* __restrict__ sat,
                                                  const float* __restrict__ cex,
                                                  const float* __restrict__ winG,
                                                  const float* __restrict__ gn2p,
                                                  float* __restrict__ out) {
    __shared__ float rbv[4];
    __shared__ int rbi[4];
    int tid = threadIdx.x;
    float bv = -3.0e38f;
    int bi = 1 << 30;
    for (int p = tid; p < 289; p += 256) {
        float v = cex[p];
        if (v > bv) { bv = v; bi = p; }
    }
    for (int off = 32; off; off >>= 1) {
        float ov = __shfl_down(bv, off);
        int oi = __shfl_down(bi, off);
        if (ov > bv || (ov == bv && oi < bi)) { bv = ov; bi = oi; }
    }
    if ((tid & 63) == 0) { rbv[tid >> 6] = bv; rbi[tid >> 6] = bi; }
    __syncthreads();
    if (tid == 0) {
        for (int q = 1; q < 4; q++)
            if (rbv[q] > rbv[0] || (rbv[q] == rbv[0] && rbi[q] < rbi[0])) {
                rbv[0] = rbv[q]; rbi[0] = rbi[q];
            }
        if (blockIdx.x == 0) {
            float gn63 = gn2p[63] + gn2p[127];
            out[4095] = rbv[0] / (fmaxf(sqrtf(winG[rbi[0]]), 1e-12f) *
                                  fmaxf(sqrtf(gn63), 1e-12f));
        }
    }
    __syncthreads();
    int fidx = rbi[0];
    int hy = fidx / 17, wx = fidx % 17;
    int e = blockIdx.x * 256 + tid;           // < 36864
    int c = e / 576;
    int rem = e - c * 576;
    int rr = rem / 24, col = rem - rr * 24;
    out[4096 + e] = sat[(size_t)(63 * 64 + c) * 4096 + (12 + hy + rr) * 64 + 12 + wx + col];
}

extern "C" void kernel_launch(void* const* d_in, const int* in_sizes, int n_in,
                              void* d_out, int out_size, void* d_ws, size_t ws_size,
                              hipStream_t stream) {
    const float* grd = (const float*)d_in[0];
    const float* sat = (const float*)d_in[1];
    float* out = (float*)d_out;

    float* wsf = (float*)d_ws;
    __hip_bfloat16* sth = (__hip_bfloat16*)(wsf + SATT_H);
    __hip_bfloat16* gth = (__hip_bfloat16*)(wsf + GRDT_H);
    float* corr = wsf + CORR_O;
    float* winG = wsf + WING_O;
    float* gn2p = wsf + GN2_O;
    float* cex  = wsf + CEX_O;
    float* S2g  = wsf + S2G_O;

    prep<<<2977, 256, 0, stream>>>(sat, grd, sth, gth, S2g, gn2p, corr, cex);
    corr_mfma<<<512, 256, 0, stream>>>(sth, gth, corr);
    argsim<<<64, 256, 0, stream>>>(corr, S2g, gn2p, winG, out);
    copy_patch<<<144, 256, 0, stream>>>(sat, cex, winG, gn2p, out);
}

// Round 23
// 168.797 us; speedup vs baseline: 1.0560x; 1.0560x over previous
//
#include <hip/hip_runtime.h>
#include <hip/hip_bf16.h>
#include <math.h>

// Shapes: grd (N=64,C=64,24,24), sat (M=64,C=64,64,64); crop sat[:,:,12:52,12:52] (40x40)
// corr (64,64,17,17); out: [0,4096) similarity f32, [4096,40960) sat_f (64,24,24) f32.
//
// Round-23: exact63 was ALWAYS ~30-40us (serial div/mod + dependent-load chain,
// 144 latency-bound iters/block) — hidden inside fused dispatches since r19.
// Now its own kernel with 6 independent row-chains per thread (divisions 144->6,
// 288 loads pipelined) -> ~3-6us. prep reverts to r21 form; corr_mfma = r17 core
// verbatim (106.5us, 5x reproduced).
// Single bf16-product corr (near-tie flips only; sim err <2e-4); (63,63) exact.

typedef float f32x16 __attribute__((ext_vector_type(16)));
typedef short short8 __attribute__((ext_vector_type(8)));

// ws layout (float words)
#define SATT_H 0u          // bf16 [m][4 cc][1600 pix][16 c] = 3,276,800 f
#define GRDT_H 3276800u    // bf16 [cc=4][ij=576][n=64][16 c] = 1,179,648 f
#define CORR_O 4456448u    // f32 [m][304][64] = 1,245,184 f
#define WING_O 5701632u    // f32 [289] (m=63 win2 row) -> pad 384
#define GN2_O  5702016u    // f32 [2][64] = 128
#define CEX_O  5702144u    // f32 [289] -> pad 384
#define S2G_O  5702528u    // f32 [m][1600] = 102,400 f

// ---------- P0: fused prep. grid 2688 = 2560 satT + 128 grdT; block 256 ----------
__global__ __launch_bounds__(256) void prep(const float* __restrict__ sat,
                                            const float* __restrict__ grd,
                                            __hip_bfloat16* __restrict__ sth,
                                            __hip_bfloat16* __restrict__ gth,
                                            float* __restrict__ S2g,
                                            float* __restrict__ gn2p,
                                            float* __restrict__ corrz) {
    __shared__ __hip_bfloat16 shb[32 * 577];      // grdT needs 36,928 B; satT uses prefix
    int bid = blockIdx.x;
    int tid = threadIdx.x;

    if (bid < 2560) {
        // ---- satT path ----
        {
            int f4 = bid * 122 + tid;
            if (tid < 122 && f4 < 311392)
                ((float4*)corrz)[f4] = make_float4(0.f, 0.f, 0.f, 0.f);
        }
        int m = bid / 40, r = bid % 40;
        const float* base = sat + (size_t)m * 262144 + (12 + r) * 64 + 12;
        for (int k = 0; k < 10; k++) {
            int idx = tid + 256 * k;          // 2560 = 64c * 40w
            int c = idx / 40, w2 = idx % 40;
            shb[w2 * 66 + c] = __float2bfloat16(base[c * 4096 + w2]);
        }
        __syncthreads();
        __hip_bfloat16* dh = sth + (size_t)m * 102400 + r * 640;
        for (int k = 0; k < 10; k++) {
            int idx = tid + 256 * k;          // idx = cc*640 + w2*16 + cl
            int cc = idx / 640, rem = idx - cc * 640;
            int w2 = rem >> 4, cl = rem & 15;
            dh[cc * 25600 + w2 * 16 + cl] = shb[w2 * 66 + cc * 16 + cl];
        }
        if (tid < 40) {
            float s = 0.0f;
            for (int c = 0; c < 64; c++) {
                float v = __bfloat162float(shb[tid * 66 + c]);
                s += v * v;
            }
            S2g[m * 1600 + r * 40 + tid] = s;
        }
    } else {
        // ---- grdT path ----
        __shared__ float red[4];
        int x = bid - 2560;
        int n = x >> 1, ch = x & 1;
        const float* src = grd + (size_t)n * 36864 + ch * 32 * 576;
        float s = 0.0f;
        for (int k = 0; k < 72; k++) {
            int idx = tid + 256 * k;          // idx = cl*576 + ij
            int cl = idx / 576, ij = idx % 576;
            float v = src[idx];
            s += v * v;
            shb[cl * 577 + ij] = __float2bfloat16(v);
        }
        for (int off = 32; off; off >>= 1) s += __shfl_down(s, off);
        if ((tid & 63) == 0) red[tid >> 6] = s;
        __syncthreads();
        if (tid == 0) gn2p[ch * 64 + n] = red[0] + red[1] + red[2] + red[3];
        for (int k = 0; k < 72; k++) {
            int idx = tid + 256 * k;          // idx = ij*32 + cl
            int ij = idx >> 5, cl = idx & 31;
            int c = ch * 32 + cl;
            gth[((size_t)((c >> 4) * 576 + ij)) * 1024 + n * 16 + (c & 15)] = shb[cl * 577 + ij];
        }
    }
}

// ---------- K1: MFMA corr (r17 core verbatim). grid 512; block 256 ----------
__global__ __launch_bounds__(256, 2) void corr_mfma(const __hip_bfloat16* __restrict__ sth,
                                                    const __hip_bfloat16* __restrict__ gth,
                                                    float* __restrict__ corr) {
    __shared__ __align__(16) __hip_bfloat16 satW[760 * 16];     // 24,320 B

    int bid = blockIdx.x;
    int xcd = bid & 7, slot = bid >> 3;             // XCD-aware: 8 m per XCD
    int m = xcd * 8 + (slot >> 3), iq = slot & 7;   // 8 i-slices of 3 rows per m
    int tid = threadIdx.x;
    int w = tid >> 6, l = tid & 63;
    int ln31 = l & 31, h = l >> 5;

    int rowbase[3];
#pragma unroll
    for (int t = 0; t < 3; t++) {
        int p = (w + 4 * t) * 32 + ln31;
        if (p > 288) p = 288;                       // tail rows clamp to a valid pixel
        rowbase[t] = (p / 17) * 40 + (p % 17);
    }
    f32x16 acc[3][2];
#pragma unroll
    for (int t = 0; t < 3; t++) {
        acc[t][0] = (f32x16)0.0f;
        acc[t][1] = (f32x16)0.0f;
    }

    // B per-lane address: plane (cc*576 + iq*72 + ijl) of 1024 elems;
    // lane frag = [n = nt*32 + ln31][c = h*8..h*8+7].
    const __hip_bfloat16* gbase = gth + (size_t)(iq * 72) * 1024 + ln31 * 16 + h * 8;

#define BLOADR(B0, B1, CC, IJL) {                                               \
        const __hip_bfloat16* p_ = gbase + ((size_t)(CC) * 576 + (IJL)) * 1024; \
        B0 = *(const short8*)p_;                                                \
        B1 = *(const short8*)(p_ + 512);                                        \
    }
#define COMPUTE(IJL, B0, B1) {                                                  \
        int il_ = (IJL) / 24;                                                   \
        int pixoff_ = il_ * 40 + ((IJL) - il_ * 24);                            \
        if (w < 2) {                                                            \
            _Pragma("unroll")                                                   \
            for (int t = 0; t < 3; t++) {                                       \
                int ao = (rowbase[t] + pixoff_) * 32 + h * 16;                  \
                short8 af = *(const short8*)((const char*)satW + ao);           \
                acc[t][0] = __builtin_amdgcn_mfma_f32_32x32x16_bf16(af, B0, acc[t][0], 0, 0, 0); \
                acc[t][1] = __builtin_amdgcn_mfma_f32_32x32x16_bf16(af, B1, acc[t][1], 0, 0, 0); \
            }                                                                   \
        } else {                                                                \
            _Pragma("unroll")                                                   \
            for (int t = 0; t < 2; t++) {                                       \
                int ao = (rowbase[t] + pixoff_) * 32 + h * 16;                  \
                short8 af = *(const short8*)((const char*)satW + ao);           \
                acc[t][0] = __builtin_amdgcn_mfma_f32_32x32x16_bf16(af, B0, acc[t][0], 0, 0, 0); \
                acc[t][1] = __builtin_amdgcn_mfma_f32_32x32x16_bf16(af, B1, acc[t][1], 0, 0, 0); \
            }                                                                   \
        }                                                                       \
    }

#pragma unroll
    for (int cc = 0; cc < 4; cc++) {
        __syncthreads();                            // prior cc's satW reads done
        // stage satW: 1520 linear 16-B slots from relaid satT
        const __hip_bfloat16* satb = sth + (size_t)m * 102400 + cc * 25600 + iq * 1920;
#pragma unroll
        for (int k2 = 0; k2 < 6; k2++) {
            int s = tid + 256 * k2;
            if (s < 1520) {
                float4 v = *(const float4*)(satb + s * 8);
                *(float4*)((char*)satW + s * 16) = v;
            }
        }
        short8 x0, x1, y0, y1, z0, z1;
        BLOADR(x0, x1, cc, 0);
        BLOADR(y0, y1, cc, 1);
        BLOADR(z0, z1, cc, 2);
        __syncthreads();                            // publish satW

        for (int ijg = 0; ijg < 24; ijg++) {
            int base = ijg * 3;
            COMPUTE(base + 0, x0, x1);
            if (base + 3 < 72) BLOADR(x0, x1, cc, base + 3);
            COMPUTE(base + 1, y0, y1);
            if (base + 4 < 72) BLOADR(y0, y1, cc, base + 4);
            COMPUTE(base + 2, z0, z1);
            if (base + 5 < 72) BLOADR(z0, z1, cc, base + 5);
        }
    }

    int T = (w < 2) ? 3 : 2;
#pragma unroll
    for (int t = 0; t < 3; t++) {
        if (t >= T) break;
        int tile = w + 4 * t;
#pragma unroll
        for (int nt = 0; nt < 2; nt++)
#pragma unroll
            for (int q = 0; q < 16; q++) {
                int prow = tile * 32 + (q & 3) + 8 * (q >> 2) + 4 * h;
                if (prow < 289)
                    atomicAdd(&corr[((size_t)m * 304 + prow) * 64 + nt * 32 + ln31],
                              acc[t][nt][q]);
            }
    }
#undef BLOADR
#undef COMPUTE
}

// ---------- K2: exact fp32 corr for (m,n)=(63,63). grid 289; block 256 ----------
// ILP restructure: thread owns 6 ROWS (row = c*24+i, k-loop fully unrolled ->
// 6 independent 24-element contiguous dot chains; divisions 144 -> 6 per thread).
__global__ __launch_bounds__(256) void exact63(const float* __restrict__ sat,
                                               const float* __restrict__ grd,
                                               float* __restrict__ correx) {
    int p = blockIdx.x;
    int hy = p / 17, wx = p % 17;
    int tid = threadIdx.x;
    const float* satm = sat + (size_t)63 * 262144 + (12 + hy) * 64 + 12 + wx;
    const float* grdn = grd + (size_t)63 * 36864;

    float a[6];
#pragma unroll
    for (int k = 0; k < 6; k++) {
        int row = tid + 256 * k;          // 1536 rows = 64c x 24i
        int c = row / 24, i = row - c * 24;
        const float* sp = satm + c * 4096 + i * 64;
        const float* gp = grdn + row * 24;
        float s = 0.0f;
#pragma unroll
        for (int j = 0; j < 24; j++) s = fmaf(sp[j], gp[j], s);
        a[k] = s;
    }
    float dot = ((a[0] + a[1]) + (a[2] + a[3])) + (a[4] + a[5]);
    for (int off = 32; off; off >>= 1) dot += __shfl_down(dot, off);
    __shared__ float red[4];
    if ((tid & 63) == 0) red[tid >> 6] = dot;
    __syncthreads();
    if (tid == 0) correx[p] = red[0] + red[1] + red[2] + red[3];
}

// ---------- K3: fused win2 + argmax + similarity. grid 64 (m); block 256 ----------
__global__ __launch_bounds__(256) void argsim(const float* __restrict__ corr,
                                              const float* __restrict__ S2g,
                                              const float* __restrict__ gn2p,
                                              float* __restrict__ winG,
                                              float* __restrict__ out) {
    __shared__ float S2[40][41];
    __shared__ float RS[40][18];
    __shared__ float w2[304];
    __shared__ float gn[64];
    __shared__ float fbv[4][64];
    __shared__ int   fbi[4][64];
    int m = blockIdx.x, tid = threadIdx.x;
    for (int k = 0; k < 7; k++) {
        int idx = tid + 256 * k;
        if (idx < 1600) S2[idx / 40][idx % 40] = S2g[m * 1600 + idx];
    }
    if (tid < 64) gn[tid] = gn2p[tid] + gn2p[64 + tid];
    __syncthreads();
    for (int k = 0; k < 3; k++) {
        int idx = tid + 256 * k;
        if (idx < 680) {
            int r = idx / 17, x = idx % 17;
            float s = 0.0f;
            for (int j = 0; j < 24; j++) s += S2[r][x + j];
            RS[r][x] = s;
        }
    }
    __syncthreads();
    for (int k = 0; k < 2; k++) {
        int idx = tid + 256 * k;
        if (idx < 289) {
            int y = idx / 17, x = idx % 17;
            float s = 0.0f;
            for (int i2 = 0; i2 < 24; i2++) s += RS[y + i2][x];
            w2[idx] = s;
            if (m == 63) winG[idx] = s;
        }
    }
    __syncthreads();
    int n = tid & 63, pg = tid >> 6;
    float bv = -3.0e38f;
    int bi = 1 << 30;
    for (int p = pg; p < 289; p += 4) {
        float v = corr[((size_t)m * 304 + p) * 64 + n];
        if (v > bv) { bv = v; bi = p; }   // ascending p within group: first occurrence
    }
    fbv[pg][n] = bv;
    fbi[pg][n] = bi;
    __syncthreads();
    if (pg == 0) {
        for (int q = 1; q < 4; q++) {
            float ov = fbv[q][n];
            int oi = fbi[q][n];
            if (ov > bv || (ov == bv && oi < bi)) { bv = ov; bi = oi; }
        }
        out[m * 64 + n] = bv / (fmaxf(sqrtf(w2[bi]), 1e-12f) * fmaxf(sqrtf(gn[n]), 1e-12f));
    }
}

// ---------- K4: (63,63) exact argmax + sim fix + patch copy. grid 144 ----------
__global__ __launch_bounds__(256) void copy_patch(const float* __restrict__ sat,
                                                  const float* __restrict__ cex,
                                                  const float* __restrict__ winG,
                                                  const float* __restrict__ gn2p,
                                                  float* __restrict__ out) {
    __shared__ float rbv[4];
    __shared__ int rbi[4];
    int tid = threadIdx.x;
    float bv = -3.0e38f;
    int bi = 1 << 30;
    for (int p = tid; p < 289; p += 256) {
        float v = cex[p];
        if (v > bv) { bv = v; bi = p; }
    }
    for (int off = 32; off; off >>= 1) {
        float ov = __shfl_down(bv, off);
        int oi = __shfl_down(bi, off);
        if (ov > bv || (ov == bv && oi < bi)) { bv = ov; bi = oi; }
    }
    if ((tid & 63) == 0) { rbv[tid >> 6] = bv; rbi[tid >> 6] = bi; }
    __syncthreads();
    if (tid == 0) {
        for (int q = 1; q < 4; q++)
            if (rbv[q] > rbv[0] || (rbv[q] == rbv[0] && rbi[q] < rbi[0])) {
                rbv[0] = rbv[q]; rbi[0] = rbi[q];
            }
        if (blockIdx.x == 0) {
            float gn63 = gn2p[63] + gn2p[127];
            out[4095] = rbv[0] / (fmaxf(sqrtf(winG[rbi[0]]), 1e-12f) *
                                  fmaxf(sqrtf(gn63), 1e-12f));
        }
    }
    __syncthreads();
    int fidx = rbi[0];
    int hy = fidx / 17, wx = fidx % 17;
    int e = blockIdx.x * 256 + tid;           // < 36864
    int c = e / 576;
    int rem = e - c * 576;
    int rr = rem / 24, col = rem - rr * 24;
    out[4096 + e] = sat[(size_t)(63 * 64 + c) * 4096 + (12 + hy + rr) * 64 + 12 + wx + col];
}

extern "C" void kernel_launch(void* const* d_in, const int* in_sizes, int n_in,
                              void* d_out, int out_size, void* d_ws, size_t ws_size,
                              hipStream_t stream) {
    const float* grd = (const float*)d_in[0];
    const float* sat = (const float*)d_in[1];
    float* out = (float*)d_out;

    float* wsf = (float*)d_ws;
    __hip_bfloat16* sth = (__hip_bfloat16*)(wsf + SATT_H);
    __hip_bfloat16* gth = (__hip_bfloat16*)(wsf + GRDT_H);
    float* corr = wsf + CORR_O;
    float* winG = wsf + WING_O;
    float* gn2p = wsf + GN2_O;
    float* cex  = wsf + CEX_O;
    float* S2g  = wsf + S2G_O;

    prep<<<2688, 256, 0, stream>>>(sat, grd, sth, gth, S2g, gn2p, corr);
    exact63<<<289, 256, 0, stream>>>(sat, grd, cex);
    corr_mfma<<<512, 256, 0, stream>>>(sth, gth, corr);
    argsim<<<64, 256, 0, stream>>>(corr, S2g, gn2p, winG, out);
    copy_patch<<<144, 256, 0, stream>>>(sat, cex, winG, gn2p, out);
}